// Round 2
// baseline (235.581 us; speedup 1.0000x reference)
//
#include <hip/hip_runtime.h>

#define SDIM 4096

typedef _Float16 half_t;
typedef __attribute__((ext_vector_type(4))) _Float16 half4;
typedef __attribute__((ext_vector_type(8))) _Float16 half8;
typedef __attribute__((ext_vector_type(4))) float f32x4;
typedef __attribute__((ext_vector_type(16))) float f32x16;

// ======================= GroupNorm =======================
__global__ __launch_bounds__(256)
void gn_kernel(const float* __restrict__ x, const float* __restrict__ gw,
               const float* __restrict__ gb, float* __restrict__ out) {
  int b = blockIdx.x >> 5;
  int g = blockIdx.x & 31;
  const float4* xp = (const float4*)(x + ((size_t)(b * 32 + g) * 8) * SDIM);
  float4* op = (float4*)(out + ((size_t)(b * 32 + g) * 8) * SDIM);
  int t = threadIdx.x;
  float sum = 0.f, ss = 0.f;
  #pragma unroll 4
  for (int i = t; i < 8192; i += 256) {
    float4 v = xp[i];
    sum += v.x + v.y + v.z + v.w;
    ss  += v.x * v.x + v.y * v.y + v.z * v.z + v.w * v.w;
  }
  #pragma unroll
  for (int off = 32; off > 0; off >>= 1) {
    sum += __shfl_down(sum, off);
    ss  += __shfl_down(ss, off);
  }
  __shared__ float s1[4], s2[4], stat[2];
  if ((t & 63) == 0) { s1[t >> 6] = sum; s2[t >> 6] = ss; }
  __syncthreads();
  if (t == 0) {
    float a = s1[0] + s1[1] + s1[2] + s1[3];
    float q = s2[0] + s2[1] + s2[2] + s2[3];
    float mean = a * (1.f / 32768.f);
    float var = q * (1.f / 32768.f) - mean * mean;
    stat[0] = mean;
    stat[1] = rsqrtf(var + 1e-5f);
  }
  __syncthreads();
  float mean = stat[0], inv = stat[1];
  #pragma unroll 4
  for (int i = t; i < 8192; i += 256) {
    int c = g * 8 + (i >> 10);
    float w = gw[c] * inv;
    float bb = gb[c] - mean * w;
    float4 v = xp[i];
    float4 o;
    o.x = v.x * w + bb;
    o.y = v.y * w + bb;
    o.z = v.z * w + bb;
    o.w = v.w * w + bb;
    op[i] = o;
  }
}

// ======================= Weight transpose (fp32) =======================
__global__ __launch_bounds__(256)
void transpose256_kernel(const float* __restrict__ in, float* __restrict__ out,
                         int rows) {
  int idx = blockIdx.x * 256 + threadIdx.x;
  int r = idx >> 8;
  int c = idx & 255;
  out[(size_t)c * rows + r] = in[idx];
}

// ======================= Tiled fp32 GEMM =======================
// C[b][m][s] = sum_k At[k][m] * B[b][k][s]
// MODE 1: fp32 out + bias + residual (out-projection)
// MODE 2: QKV epilogue -> Q (f16, x0.125, [b][n][s][64]), K (f16, [b][n][s][64]),
//         V (f16, [b][n][64][s])
template<int M, int MODE>
__global__ __launch_bounds__(256)
void gemm_kernel(const float* __restrict__ At, const float* __restrict__ Bm,
                 float* __restrict__ Cm, const float* __restrict__ bias,
                 const float* __restrict__ resid,
                 half_t* __restrict__ qT, half_t* __restrict__ kT,
                 half_t* __restrict__ vT) {
  __shared__ float As[16][68];
  __shared__ float Bs[16][68];
  int n0 = blockIdx.x * 64;
  int m0 = blockIdx.y * 64;
  int b  = blockIdx.z;
  const float* Bb = Bm + (size_t)b * 256 * SDIM;
  int t  = threadIdx.x;
  int tx = t & 15, ty = t >> 4;
  int lr = t >> 4, lc = (t & 15) * 4;
  float acc[4][4] = {};
  for (int k0 = 0; k0 < 256; k0 += 16) {
    float4 av = *(const float4*)(At + (size_t)(k0 + lr) * M + m0 + lc);
    float4 bv = *(const float4*)(Bb + (size_t)(k0 + lr) * SDIM + n0 + lc);
    __syncthreads();
    *(float4*)&As[lr][lc] = av;
    *(float4*)&Bs[lr][lc] = bv;
    __syncthreads();
    #pragma unroll
    for (int k = 0; k < 16; k++) {
      float4 a  = *(const float4*)&As[k][ty * 4];
      float4 bb = *(const float4*)&Bs[k][tx * 4];
      acc[0][0] = fmaf(a.x, bb.x, acc[0][0]);
      acc[0][1] = fmaf(a.x, bb.y, acc[0][1]);
      acc[0][2] = fmaf(a.x, bb.z, acc[0][2]);
      acc[0][3] = fmaf(a.x, bb.w, acc[0][3]);
      acc[1][0] = fmaf(a.y, bb.x, acc[1][0]);
      acc[1][1] = fmaf(a.y, bb.y, acc[1][1]);
      acc[1][2] = fmaf(a.y, bb.z, acc[1][2]);
      acc[1][3] = fmaf(a.y, bb.w, acc[1][3]);
      acc[2][0] = fmaf(a.z, bb.x, acc[2][0]);
      acc[2][1] = fmaf(a.z, bb.y, acc[2][1]);
      acc[2][2] = fmaf(a.z, bb.z, acc[2][2]);
      acc[2][3] = fmaf(a.z, bb.w, acc[2][3]);
      acc[3][0] = fmaf(a.w, bb.x, acc[3][0]);
      acc[3][1] = fmaf(a.w, bb.y, acc[3][1]);
      acc[3][2] = fmaf(a.w, bb.z, acc[3][2]);
      acc[3][3] = fmaf(a.w, bb.w, acc[3][3]);
    }
  }
  if (MODE == 1) {
    #pragma unroll
    for (int i = 0; i < 4; i++) {
      int m = m0 + ty * 4 + i;
      size_t off = ((size_t)b * M + m) * SDIM + n0 + tx * 4;
      float bb = bias[m];
      float4 xr = *(const float4*)(resid + off);
      float4 r;
      r.x = acc[i][0] + bb + xr.x;
      r.y = acc[i][1] + bb + xr.y;
      r.z = acc[i][2] + bb + xr.z;
      r.w = acc[i][3] + bb + xr.w;
      *(float4*)(Cm + off) = r;
    }
  } else {
    // MODE 2: m-tile is 64-aligned and lies wholly in one of Q/K/V of one head
    int head = m0 / 192;
    int kind = (m0 - head * 192) >> 6;   // 0=Q 1=K 2=V
    int dloc = ty * 4;
    int token = n0 + tx * 4;
    if (kind == 2) {
      half_t* vb = vT + ((size_t)(b * 4 + head) * 64) * SDIM;
      #pragma unroll
      for (int i = 0; i < 4; i++) {
        half4 h;
        h[0] = (half_t)acc[i][0]; h[1] = (half_t)acc[i][1];
        h[2] = (half_t)acc[i][2]; h[3] = (half_t)acc[i][3];
        *(half4*)(vb + (size_t)(dloc + i) * SDIM + token) = h;
      }
    } else {
      float scl = (kind == 0) ? 0.125f : 1.0f;
      half_t* base = (kind == 0 ? qT : kT) + ((size_t)(b * 4 + head) * SDIM) * 64;
      #pragma unroll
      for (int j = 0; j < 4; j++) {
        half4 h;
        h[0] = (half_t)(acc[0][j] * scl); h[1] = (half_t)(acc[1][j] * scl);
        h[2] = (half_t)(acc[2][j] * scl); h[3] = (half_t)(acc[3][j] * scl);
        *(half4*)(base + (size_t)(token + j) * 64 + dloc) = h;
      }
    }
  }
}

// ======================= Flash attention (f16 MFMA) =======================
// Block: 128 queries of one (b, head); 256 threads = 4 waves, 32 q-cols/wave.
// S^T = mfma(K_frag, Q_frag) -> per-lane full rows -> in-lane softmax.
// LDS tiles [token][72 f16] (144B pitch): conflict-free b128 frag reads.
__global__ __launch_bounds__(256)
void flash_kernel(const half_t* __restrict__ qT, const half_t* __restrict__ kT,
                  const half_t* __restrict__ vT, float* __restrict__ aout) {
  __shared__ __align__(16) unsigned char smem[55808];
  half_t* Qs = (half_t*)smem;              // [128][72]
  half_t* Ks = (half_t*)(smem + 18432);    // [64][72]
  half_t* Vs = (half_t*)(smem + 27648);    // [64][72]  rows = d, cols = k
  half_t* Pl = (half_t*)(smem + 36864);    // [128][72] rows = q, cols = k
  float*  scl = (float*)(smem + 55296);    // [128]

  const int t = threadIdx.x;
  const int l = t & 63;
  const int wq = t >> 6;      // wave's q strip [wq*32, wq*32+32)
  const int h2 = l >> 5;
  const int lq = l & 31;

  const int qb = blockIdx.x;
  const int n = blockIdx.y, b = blockIdx.z;
  const size_t hoff = ((size_t)(b * 4 + n)) * SDIM * 64;
  const half_t* qbp = qT + hoff;   // [4096][64]
  const half_t* kbp = kT + hoff;   // [4096][64]
  const half_t* vbp = vT + hoff;   // [64][4096]

  const int srow = t >> 3;          // 0..31
  const int schk = (t & 7) * 8;     // f16 col offset

  // ---- Q tile (once) + prefetch K/V tile 0 ----
  uint4 qreg0 = *(const uint4*)(qbp + ((size_t)(qb * 128 + srow)) * 64 + schk);
  uint4 qreg1 = *(const uint4*)(qbp + ((size_t)(qb * 128 + srow + 32)) * 64 + schk);
  uint4 qreg2 = *(const uint4*)(qbp + ((size_t)(qb * 128 + srow + 64)) * 64 + schk);
  uint4 qreg3 = *(const uint4*)(qbp + ((size_t)(qb * 128 + srow + 96)) * 64 + schk);
  uint4 kreg0 = *(const uint4*)(kbp + ((size_t)srow) * 64 + schk);
  uint4 kreg1 = *(const uint4*)(kbp + ((size_t)(srow + 32)) * 64 + schk);
  uint4 vreg0 = *(const uint4*)(vbp + ((size_t)srow) * SDIM + schk);
  uint4 vreg1 = *(const uint4*)(vbp + ((size_t)(srow + 32)) * SDIM + schk);
  *(uint4*)(Qs + (srow      ) * 72 + schk) = qreg0;
  *(uint4*)(Qs + (srow + 32 ) * 72 + schk) = qreg1;
  *(uint4*)(Qs + (srow + 64 ) * 72 + schk) = qreg2;
  *(uint4*)(Qs + (srow + 96 ) * 72 + schk) = qreg3;

  f32x16 O0, O1;
  #pragma unroll
  for (int i = 0; i < 16; i++) { O0[i] = 0.f; O1[i] = 0.f; }
  float m_run = -INFINITY, l_run = 0.f;

  const int qrow = wq * 32 + lq;    // this lane's q (block-local)

  for (int kt = 0; kt < 64; kt++) {
    // stage K/V from prefetch regs
    *(uint4*)(Ks + (srow     ) * 72 + schk) = kreg0;
    *(uint4*)(Ks + (srow + 32) * 72 + schk) = kreg1;
    *(uint4*)(Vs + (srow     ) * 72 + schk) = vreg0;
    *(uint4*)(Vs + (srow + 32) * 72 + schk) = vreg1;
    if (kt < 63) {
      kreg0 = *(const uint4*)(kbp + ((size_t)((kt + 1) * 64 + srow)) * 64 + schk);
      kreg1 = *(const uint4*)(kbp + ((size_t)((kt + 1) * 64 + srow + 32)) * 64 + schk);
      vreg0 = *(const uint4*)(vbp + ((size_t)srow) * SDIM + (kt + 1) * 64 + schk);
      vreg1 = *(const uint4*)(vbp + ((size_t)(srow + 32)) * SDIM + (kt + 1) * 64 + schk);
    }
    __syncthreads();

    // ---- scores: S^T[64k x 32q] per wave ----
    f32x16 s0, s1;
    #pragma unroll
    for (int i = 0; i < 16; i++) { s0[i] = 0.f; s1[i] = 0.f; }
    #pragma unroll
    for (int ds = 0; ds < 4; ds++) {
      half8 aq  = *(const half8*)(Qs + qrow * 72 + ds * 16 + h2 * 8);
      half8 ak0 = *(const half8*)(Ks + lq * 72 + ds * 16 + h2 * 8);
      half8 ak1 = *(const half8*)(Ks + (32 + lq) * 72 + ds * 16 + h2 * 8);
      s0 = __builtin_amdgcn_mfma_f32_32x32x16_f16(ak0, aq, s0, 0, 0, 0);
      s1 = __builtin_amdgcn_mfma_f32_32x32x16_f16(ak1, aq, s1, 0, 0, 0);
    }

    // ---- in-lane online softmax (lane holds 32 of 64 k for its q) ----
    float mx = s0[0];
    #pragma unroll
    for (int i = 1; i < 16; i++) mx = fmaxf(mx, s0[i]);
    #pragma unroll
    for (int i = 0; i < 16; i++) mx = fmaxf(mx, s1[i]);
    mx = fmaxf(mx, __shfl_xor(mx, 32));
    float mnew = fmaxf(m_run, mx);
    float scale = __expf(m_run - mnew);
    m_run = mnew;
    float sum = 0.f;
    #pragma unroll
    for (int i = 0; i < 16; i++) { s0[i] = __expf(s0[i] - mnew); sum += s0[i]; }
    #pragma unroll
    for (int i = 0; i < 16; i++) { s1[i] = __expf(s1[i] - mnew); sum += s1[i]; }
    sum += __shfl_xor(sum, 32);
    l_run = l_run * scale + sum;
    scl[qrow] = scale;

    // ---- write P as f16: k = 32*kt + 8*rq + 4*h2 + (0..3) ----
    #pragma unroll
    for (int rq = 0; rq < 4; rq++) {
      half4 h0, h1;
      h0[0] = (half_t)s0[4*rq];     h0[1] = (half_t)s0[4*rq + 1];
      h0[2] = (half_t)s0[4*rq + 2]; h0[3] = (half_t)s0[4*rq + 3];
      h1[0] = (half_t)s1[4*rq];     h1[1] = (half_t)s1[4*rq + 1];
      h1[2] = (half_t)s1[4*rq + 2]; h1[3] = (half_t)s1[4*rq + 3];
      *(half4*)(Pl + qrow * 72 + 8 * rq + 4 * h2)      = h0;
      *(half4*)(Pl + qrow * 72 + 32 + 8 * rq + 4 * h2) = h1;
    }

    // ---- rescale O by per-row scale (broadcast via LDS) ----
    #pragma unroll
    for (int rq = 0; rq < 4; rq++) {
      f32x4 s4 = *(const f32x4*)&scl[wq * 32 + 8 * rq + 4 * h2];
      #pragma unroll
      for (int j = 0; j < 4; j++) {
        O0[4*rq + j] *= s4[j];
        O1[4*rq + j] *= s4[j];
      }
    }

    // ---- PV: O[32q x 64d] per wave ----
    #pragma unroll
    for (int ks = 0; ks < 4; ks++) {
      half8 ap  = *(const half8*)(Pl + qrow * 72 + ks * 16 + h2 * 8);
      half8 bv0 = *(const half8*)(Vs + lq * 72 + ks * 16 + h2 * 8);
      half8 bv1 = *(const half8*)(Vs + (32 + lq) * 72 + ks * 16 + h2 * 8);
      O0 = __builtin_amdgcn_mfma_f32_32x32x16_f16(ap, bv0, O0, 0, 0, 0);
      O1 = __builtin_amdgcn_mfma_f32_32x32x16_f16(ap, bv1, O1, 0, 0, 0);
    }
    __syncthreads();
  }

  // ---- finalize: divide by l, stage to LDS (transpose), coalesced store ----
  scl[qrow] = 1.0f / l_run;
  __syncthreads();     // also: all PV frag reads done before aliasing smem
  float* Olds = (float*)smem;    // [64][132]
  #pragma unroll
  for (int rq = 0; rq < 4; rq++) {
    f32x4 li = *(const f32x4*)&scl[wq * 32 + 8 * rq + 4 * h2];
    #pragma unroll
    for (int j = 0; j < 4; j++) {
      int qp = 8 * rq + 4 * h2 + j;
      Olds[lq * 132 + wq * 32 + qp]        = O0[4*rq + j] * li[j];
      Olds[(32 + lq) * 132 + wq * 32 + qp] = O1[4*rq + j] * li[j];
    }
  }
  __syncthreads();
  float* ob = aout + ((size_t)(b * 4 + n) * 64) * SDIM + qb * 128;
  #pragma unroll
  for (int rr = 0; rr < 8; rr++) {
    int c = (t >> 5) + 8 * rr;
    int tok = (t & 31) * 4;
    *(float4*)(ob + (size_t)c * SDIM + tok) = *(const float4*)&Olds[c * 132 + tok];
  }
}

// ======================= launch =======================
extern "C" void kernel_launch(void* const* d_in, const int* in_sizes, int n_in,
                              void* d_out, int out_size, void* d_ws, size_t ws_size,
                              hipStream_t stream) {
  const float* x      = (const float*)d_in[0];
  const float* norm_w = (const float*)d_in[1];
  const float* norm_b = (const float*)d_in[2];
  const float* qkv_w  = (const float*)d_in[3];
  const float* out_w  = (const float*)d_in[4];
  const float* out_b  = (const float*)d_in[5];
  float* outp = (float*)d_out;

  // ws layout (floats):
  // norm/attn buf [2*256*4096] | qkvwT [256*768] | outwT [256*256] |
  // f16 region: QT | KT | VT  (each 2*4*4096*64 halves = 1,048,576 floats)
  float* ws       = (float*)d_ws;
  float* norm_buf = ws;
  float* qkvwT    = norm_buf + (size_t)2 * 256 * SDIM;
  float* outwT    = qkvwT + 768 * 256;
  half_t* qT      = (half_t*)(outwT + 256 * 256);
  half_t* kT      = qT + (size_t)2 * 4 * SDIM * 64;
  half_t* vT      = kT + (size_t)2 * 4 * SDIM * 64;

  transpose256_kernel<<<768, 256, 0, stream>>>(qkv_w, qkvwT, 768);
  transpose256_kernel<<<256, 256, 0, stream>>>(out_w, outwT, 256);
  gn_kernel<<<64, 256, 0, stream>>>(x, norm_w, norm_b, norm_buf);
  gemm_kernel<768, 2><<<dim3(64, 12, 2), 256, 0, stream>>>(
      qkvwT, norm_buf, nullptr, nullptr, nullptr, qT, kT, vT);
  flash_kernel<<<dim3(32, 4, 2), 256, 0, stream>>>(qT, kT, vT, norm_buf);
  gemm_kernel<256, 1><<<dim3(64, 4, 2), 256, 0, stream>>>(
      outwT, norm_buf, outp, out_b, x, nullptr, nullptr, nullptr);
}